// Round 7
// baseline (968.103 us; speedup 1.0000x reference)
//
#include <hip/hip_runtime.h>

// Problem constants
#define NROWS   16384      // 16*32*32 flattened (b,h,w) rows
#define KCODES  8192
#define CDIM    256
#define HWS     1024       // 32*32
#define BSTRIDE 262144     // 256*1024 floats per batch in z / out

// Workspace layout (float-unit offsets) -- 8 slices
#define WS_AN   0                         // ||x||^2 per row       [16384]
#define WS_CE   16384                     // ||e||^2 per code      [8192]
#define WS_CD   24576                     // cand dist [n*8+slice] [131072]
#define WS_CI   155648                    // cand idx  (int)       [131072]
#define WS_IDX  286720                    // final idx (int)       [16384]
#define WS_LOSS 303104                    // loss accumulator      [1]

typedef float f32x2 __attribute__((ext_vector_type(2)));
typedef float f32x4 __attribute__((ext_vector_type(4)));

// v_pk_fma_f32: two independent fp32 FMAs per instruction. Rounds 8-9 verified
// bit-exact vs scalar chain (absmax 0). Measured ~4.8 cyc/instr (RF-port bound)
// -> kernel VALU-busy floor ~527-550us.
// R10 LESSON: launch_bounds min-waves>2 spilled the asm-pair accs (WRITE_SIZE
// 2048->4e6). Keep (256,2).
// R11 LESSON: occupancy is pinned at ~2 blocks/CU regardless of LDS 32/48KB and
// grid 512/1024 (20.8/19.6/20.9% across rounds) -- occupancy lever is dead.
// R12: attack the 317us idle directly: async-STAGE split (T14). Issue each
// iteration's 12 global loads BEFORE the ~1300-cyc compute of the previous
// iteration, so L2/HBM latency hides under compute instead of being exposed
// at the vmcnt(0) drain before ds_write.
#define PKFMA_LO(acc, a, b) \
  asm("v_pk_fma_f32 %0, %1, %2, %0 op_sel:[0,0,0] op_sel_hi:[0,1,1]" \
      : "+v"(acc) : "v"(a), "v"(b))
#define PKFMA_HI(acc, a, b) \
  asm("v_pk_fma_f32 %0, %1, %2, %0 op_sel:[1,0,0] op_sel_hi:[1,1,1]" \
      : "+v"(acc) : "v"(a), "v"(b))

// -------- row norms, replicating numpy pairwise_sum order exactly --------
__global__ void rownorm_z_k(const float* __restrict__ z, float* __restrict__ An) {
#pragma clang fp contract(off)
  int n = blockIdx.x * 256 + threadIdx.x;                    // 16384 threads
  const float* base = z + ((size_t)(n >> 10)) * BSTRIDE + (n & 1023);
  float hs[2];
  for (int h = 0; h < 2; ++h) {
    float r[8];
#pragma unroll
    for (int j = 0; j < 8; ++j) { float v = base[(size_t)(h * 128 + j) * HWS]; r[j] = v * v; }
    for (int m = 1; m < 16; ++m) {
#pragma unroll
      for (int j = 0; j < 8; ++j) { float v = base[(size_t)(h * 128 + m * 8 + j) * HWS]; r[j] += v * v; }
    }
    hs[h] = ((r[0] + r[1]) + (r[2] + r[3])) + ((r[4] + r[5]) + (r[6] + r[7]));
  }
  An[n] = hs[0] + hs[1];
}

__global__ void rownorm_e_k(const float* __restrict__ emb, float* __restrict__ Ce) {
#pragma clang fp contract(off)
  int n = blockIdx.x * 256 + threadIdx.x;                    // 8192 threads
  const float* base = emb + (size_t)n * CDIM;
  float hs[2];
  for (int h = 0; h < 2; ++h) {
    float r[8];
#pragma unroll
    for (int j = 0; j < 8; ++j) { float v = base[h * 128 + j]; r[j] = v * v; }
    for (int m = 1; m < 16; ++m) {
#pragma unroll
      for (int j = 0; j < 8; ++j) { float v = base[h * 128 + m * 8 + j]; r[j] += v * v; }
    }
    hs[h] = ((r[0] + r[1]) + (r[2] + r[3])) + ((r[4] + r[5]) + (r[6] + r[7]));
  }
  Ce[n] = hs[0] + hs[1];
}

// -------- fused distance + argmin (round 12: async-STAGE split) -------------
// 1024 blocks = 128 row-tiles (128 rows) x 8 code-slices (1024 codes each).
// slice = bid&7 -> natural XCD affinity (dispatch round-robins bid%8 over the
// 8 XCDs; each XCD's 1MB emb slice stays L2-resident).
// Flattened loop it=0..31 (kc = it>>3, sc = it&7). Per iteration:
//   barrier A (prior compute done) -> ds_write staged regs -> barrier B ->
//   ISSUE next iteration's 12 global loads -> sched_barrier -> compute ->
//   (it&7==7) fold.
// The loads' latency hides under the 2048-pk_fma compute; the vmcnt drain at
// the next iteration's ds_write is then ~free. Regs: pa/pb 48 live across
// compute; est ~200-230 total (cap 256 at (256,2)).
// Compute core byte-identical to rounds 9-11 (absmax must stay 0):
//   A: As[row][32c], col=((kg^((row>>3)&7))<<2)|wi; conflict-free reads.
//   B: pair-interleaved [pair][32k][2codes], granule-swizzled by pair&7;
//   one ds_read_b128 = two packed operands. 8x16 micro-tile, g ascending,
//   k3-first 4-k chains, ci-ascending strict-< compares.
// WRITE_SIZE ~8192 is the no-spill tripwire (r10: spill showed as 4e6).
__global__ void __launch_bounds__(256, 2)
vq_argmin_k(const float* __restrict__ z, const float* __restrict__ emb,
            const float* __restrict__ An, const float* __restrict__ Ce,
            float* __restrict__ cand_d, int* __restrict__ cand_i) {
  __shared__ float smem[12288];    // 48 KB: As=[0,4096), Bs=[4096,12288)
  float* As = smem;                // [128 rows][32 c], col XOR-swizzled by (row>>3)&7
  float* Bs = smem + 4096;         // [128 pairs][32 k][2 codes], granule-swizzled by pair&7

  const int t  = threadIdx.x;
  const int tx = t & 15;           // code group (16 codes, stride 16)
  const int ty = t >> 4;           // row group (8 consecutive rows)
  const int bid   = blockIdx.x;
  const int slice = bid & 7;       // slice s -> XCD s
  const int tile  = bid >> 3;
  const int rbase = tile * 128;    // never crosses the 1024-hw batch edge
  const int k0    = slice * 1024;

  const float* zb = z + ((size_t)(rbase >> 10)) * BSTRIDE + (rbase & 1023);

  float best[8];
  int   bidx[8];
#pragma unroll
  for (int ri = 0; ri < 8; ++ri) { best[ri] = 3.4028235e38f; bidx[ri] = 0; }

  f32x2 acc2[8][8];                // [ri][ci2]: .x = code tx+32*ci2, .y = +16
#pragma unroll
  for (int ri = 0; ri < 8; ++ri)
#pragma unroll
    for (int j = 0; j < 8; ++j) acc2[ri][j] = (f32x2){0.f, 0.f};

  // staging thread mappings (A identical to rounds 1-11)
  const int a_c   = t >> 4;         // stages c_locals {a_c, a_c+16}, 8 rows each
  const int a_hw  = (t & 15) * 8;   // 8 consecutive rows
  const int a_swr = (t & 15) & 7;   // (row>>3)&7 for all 8 staged rows
  const int a_wi  = a_c & 3;
  const int a_kg1 = a_c >> 2;       // k-group of c1 (c2 = +4)
  const int acol1 = ((a_kg1 ^ a_swr) << 2) | a_wi;        // const per thread
  const int acol2 = (((a_kg1 + 4) ^ a_swr) << 2) | a_wi;
  // B staging: thread loads 16 consecutive c of one emb row, twice (codes
  // b_code and b_code+128), scattering into the pair-interleaved layout.
  const int b_code = t >> 1;        // code 0..127 (pass adds +128)
  const int b_cb   = (t & 1) * 16;  // c_local base 0 or 16
  const int b_p    = ((b_code >> 5) << 4) | (b_code & 15); // pair row 0..63
  const int b_s    = (b_code >> 4) & 1;                    // which half of pair
  const int b_p7   = b_code & 7;                           // == pair&7 (pass-invariant)
  const int b_base = b_p * 64 + ((b_cb >> 1) << 2) + b_s;  // float units; pass1 += 4096

  const int rd_a_sw = ty & 7;
  const int rd_b_sw = tx & 7;       // == pair&7 for all this thread's pair rows
  const int bB      = tx * 64;      // pair-row base (ci2*1024 folds into offset)

  // prefetch registers: live across the compute phase (T14 issue-early)
  float4 pa0, pa1, pa2, pa3, pb0, pb1, pb2, pb3, pb4, pb5, pb6, pb7;
  auto issue_load = [&](int it2) {
    const int sc2 = it2 & 7;
    const int kb2 = k0 + (it2 >> 3) * 256;
    const float* zsrc = zb + (size_t)(sc2 * 32 + a_c) * HWS + a_hw;
    pa0 = *(const float4*)(zsrc);
    pa1 = *(const float4*)(zsrc + 4);
    pa2 = *(const float4*)(zsrc + 16 * HWS);
    pa3 = *(const float4*)(zsrc + 16 * HWS + 4);
    const float* bsrc0 = emb + (size_t)(kb2 + b_code) * CDIM + sc2 * 32 + b_cb;
    const float* bsrc1 = bsrc0 + (size_t)128 * CDIM;
    pb0 = *(const float4*)(bsrc0);
    pb1 = *(const float4*)(bsrc0 + 4);
    pb2 = *(const float4*)(bsrc0 + 8);
    pb3 = *(const float4*)(bsrc0 + 12);
    pb4 = *(const float4*)(bsrc1);
    pb5 = *(const float4*)(bsrc1 + 4);
    pb6 = *(const float4*)(bsrc1 + 8);
    pb7 = *(const float4*)(bsrc1 + 12);
  };

  issue_load(0);                     // prologue

#pragma unroll 1
  for (int it = 0; it < 32; ++it) {
    __syncthreads();                      // barrier A: prior compute done
    {
      // A transpose-store: 16 scalar stores, col const per thread (2-way free)
      const float va0[8] = {pa0.x, pa0.y, pa0.z, pa0.w, pa1.x, pa1.y, pa1.z, pa1.w};
      const float va1[8] = {pa2.x, pa2.y, pa2.z, pa2.w, pa3.x, pa3.y, pa3.z, pa3.w};
#pragma unroll
      for (int j = 0; j < 8; ++j) {
        const int rb = (a_hw + j) << 5;
        As[rb + acol1] = va0[j];
        As[rb + acol2] = va1[j];
      }
      // B pair-scatter, two passes (codes +0 / +128): stride-2 pairs merge
      // into ds_write2_b32. ~4-way conflicts; stores are 1/6 of LDS ops.
      const float bval0[16] = {pb0.x, pb0.y, pb0.z, pb0.w,
                               pb1.x, pb1.y, pb1.z, pb1.w,
                               pb2.x, pb2.y, pb2.z, pb2.w,
                               pb3.x, pb3.y, pb3.z, pb3.w};
      const float bval1[16] = {pb4.x, pb4.y, pb4.z, pb4.w,
                               pb5.x, pb5.y, pb5.z, pb5.w,
                               pb6.x, pb6.y, pb6.z, pb6.w,
                               pb7.x, pb7.y, pb7.z, pb7.w};
#pragma unroll
      for (int i = 0; i < 8; ++i) {
        const int off = b_base + ((i ^ b_p7) << 2);
        Bs[off]            = bval0[2 * i];
        Bs[off + 2]        = bval0[2 * i + 1];
        Bs[off + 4096]     = bval1[2 * i];
        Bs[off + 4096 + 2] = bval1[2 * i + 1];
      }
    }
    __syncthreads();                      // barrier B: staged data visible

    // issue NEXT iteration's global loads now; latency hides under compute
    if (it + 1 < 32) issue_load(it + 1);
    __builtin_amdgcn_sched_barrier(0);    // pin loads above the compute

    // 8x16 micro-tile over 32 k: 2048 pk_fma, 64 A + 128 B b128 reads.
    // A fragments hoisted (av[8], static-indexed) so B quads stay transient.
#pragma unroll
    for (int g = 0; g < 8; ++g) {
      f32x4 av[8];
#pragma unroll
      for (int ri = 0; ri < 8; ++ri)
        av[ri] = *(const f32x4*)&As[((ty * 8 + ri) << 5) + ((g ^ rd_a_sw) << 2)];
      const int sw0 = ((2 * g) ^ rd_b_sw) << 2;   // granule 2g   (k 4g,4g+1)
      const int sw1 = sw0 ^ 4;                    // granule 2g+1 (k 4g+2,4g+3)
#pragma unroll
      for (int ci2 = 0; ci2 < 8; ++ci2) {
        const f32x4 b0 = *(const f32x4*)&Bs[bB + ci2 * 1024 + sw0];
        const f32x4 b1 = *(const f32x4*)&Bs[bB + ci2 * 1024 + sw1];
        const f32x2 bk0 = __builtin_shufflevector(b0, b0, 0, 1);
        const f32x2 bk1 = __builtin_shufflevector(b0, b0, 2, 3);
        const f32x2 bk2 = __builtin_shufflevector(b1, b1, 0, 1);
        const f32x2 bk3 = __builtin_shufflevector(b1, b1, 2, 3);
#pragma unroll
        for (int ri = 0; ri < 8; ++ri) {
          const f32x2 a01 = __builtin_shufflevector(av[ri], av[ri], 0, 1);
          const f32x2 a23 = __builtin_shufflevector(av[ri], av[ri], 2, 3);
          // 4-k group, k3-first chain: identical lane math to rounds 1-11
          PKFMA_HI(acc2[ri][ci2], a23, bk3);
          PKFMA_LO(acc2[ri][ci2], a23, bk2);
          PKFMA_HI(acc2[ri][ci2], a01, bk1);
          PKFMA_LO(acc2[ri][ci2], a01, bk0);
        }
      }
    }

    // fold per kc: dist = (A - 2*dot) + C with np's elementwise fp32 rounding.
    // compare order = ci ascending (ci2 .x then .y) -> identical lowest-index
    // tie semantics; cross-thread/slice merges compare indices explicitly.
    if ((it & 7) == 7) {
      const int kbase = k0 + (it >> 3) * 256;
      const int kkb = kbase + tx;
      float cearr[16];
#pragma unroll
      for (int ci = 0; ci < 16; ++ci) cearr[ci] = Ce[kkb + ci * 16];
#pragma unroll
      for (int ri = 0; ri < 8; ++ri) {
        const float Ar = An[rbase + ty * 8 + ri];   // reload (saves live regs)
#pragma unroll
        for (int ci2 = 0; ci2 < 8; ++ci2) {
          const float d0 = (Ar - 2.0f * acc2[ri][ci2].x) + cearr[2 * ci2];
          if (d0 < best[ri]) { best[ri] = d0; bidx[ri] = kkb + ci2 * 32; }
          const float d1 = (Ar - 2.0f * acc2[ri][ci2].y) + cearr[2 * ci2 + 1];
          if (d1 < best[ri]) { best[ri] = d1; bidx[ri] = kkb + ci2 * 32 + 16; }
          acc2[ri][ci2] = (f32x2){0.f, 0.f};
        }
      }
    }
  }

  // cross-thread argmin per row (tie -> lower absolute index); alias smem
  __syncthreads();                 // compute done; safe to overwrite As/Bs
  float* redd = smem;              // [128][16]
  int*   redi = (int*)(smem + 2048);
#pragma unroll
  for (int ri = 0; ri < 8; ++ri) {
    redd[(ty * 8 + ri) * 16 + tx] = best[ri];
    redi[(ty * 8 + ri) * 16 + tx] = bidx[ri];
  }
  __syncthreads();
  if (t < 128) {
    float bd = redd[t * 16];
    int   bi = redi[t * 16];
    for (int j = 1; j < 16; ++j) {
      const float d  = redd[t * 16 + j];
      const int   i2 = redi[t * 16 + j];
      if (d < bd || (d == bd && i2 < bi)) { bd = d; bi = i2; }
    }
    const int n = rbase + t;
    cand_d[n * 8 + slice] = bd;
    cand_i[n * 8 + slice] = bi;
  }
}

// -------- merge the 8 code-slices (tie -> lower index) --------
__global__ void vq_merge_k(const float* __restrict__ cand_d, const int* __restrict__ cand_i,
                           int* __restrict__ idx_final, float* __restrict__ idxf_out) {
  const int n = blockIdx.x * 256 + threadIdx.x;   // 16384
  float bd = cand_d[n * 8];
  int   bi = cand_i[n * 8];
#pragma unroll
  for (int s = 1; s < 8; ++s) {
    const float d  = cand_d[n * 8 + s];
    const int   i2 = cand_i[n * 8 + s];
    if (d < bd || (d == bd && i2 < bi)) { bd = d; bi = i2; }
  }
  idx_final[n] = bi;
  idxf_out[n] = (float)bi;
}

// -------- gather quantized, write straight-through output, accumulate loss ----
// quantized_st = z + (q - z) in fp32 (matches np rounding; != q exactly).
__launch_bounds__(256)
__global__ void vq_gather_loss_k(const float* __restrict__ z, const float* __restrict__ emb,
                                 const int* __restrict__ idx_final,
                                 float* __restrict__ qout, float* __restrict__ loss_acc) {
  __shared__ float Qs[32 * 260];
  __shared__ int   kidx[32];
  __shared__ float warp_s[4];
  const int t = threadIdx.x;
  const int rbase = blockIdx.x * 32;
  if (t < 32) kidx[t] = idx_final[rbase + t];
  __syncthreads();
  {
    const int r = t >> 3, cp = t & 7;
    const float4* er = (const float4*)(emb + (size_t)kidx[r] * CDIM);
#pragma unroll
    for (int j = 0; j < 8; ++j) {
      const int c4 = cp + j * 8;
      const float4 v = er[c4];
      *(float4*)&Qs[r * 260 + c4 * 4] = v;
    }
  }
  __syncthreads();
  const int b = rbase >> 10, hw0 = rbase & 1023;
  const float* zb = z + (size_t)b * BSTRIDE + hw0;
  float* qb = qout + (size_t)b * BSTRIDE + hw0;
  float s = 0.f;
  const int hwl = t & 31, cg = t >> 5;
  for (int i = 0; i < 32; ++i) {
    const int c = cg * 32 + i;
    const float q  = Qs[hwl * 260 + c];
    const size_t off = (size_t)c * HWS + hwl;
    const float zv = zb[off];
    const float d  = q - zv;
    qb[off] = zv + d;          // straight-through value, np rounding
    s += d * d;
  }
  for (int off = 32; off; off >>= 1) s += __shfl_down(s, off, 64);
  if ((t & 63) == 0) warp_s[t >> 6] = s;
  __syncthreads();
  if (t == 0) atomicAdd(loss_acc, warp_s[0] + warp_s[1] + warp_s[2] + warp_s[3]);
}

__global__ void vq_finalize_k(const float* __restrict__ loss_acc, float* __restrict__ out_loss) {
  const float m = loss_acc[0] * (1.0f / 4194304.0f);
  out_loss[0] = m;          // codebook_loss
  out_loss[1] = 0.25f * m;  // commitment_loss (BETA * same mean)
}

extern "C" void kernel_launch(void* const* d_in, const int* in_sizes, int n_in,
                              void* d_out, int out_size, void* d_ws, size_t ws_size,
                              hipStream_t stream) {
  (void)in_sizes; (void)n_in; (void)out_size; (void)ws_size;
  const float* z   = (const float*)d_in[0];
  const float* emb = (const float*)d_in[1];
  float* out      = (float*)d_out;
  float* q_out    = out;                 // [16,256,32,32]
  float* loss_out = out + 4194304;       // 2 scalars
  float* idxf_out = out + 4194306;       // [16,32,32] as float

  float* ws       = (float*)d_ws;
  float* An       = ws + WS_AN;
  float* Ce       = ws + WS_CE;
  float* cand_d   = ws + WS_CD;
  int*   cand_i   = (int*)(ws + WS_CI);
  int*   idx_fin  = (int*)(ws + WS_IDX);
  float* loss_acc = ws + WS_LOSS;

  hipMemsetAsync(loss_acc, 0, sizeof(float), stream);
  rownorm_z_k<<<64, 256, 0, stream>>>(z, An);
  rownorm_e_k<<<32, 256, 0, stream>>>(emb, Ce);
  vq_argmin_k<<<1024, 256, 0, stream>>>(z, emb, An, Ce, cand_d, cand_i);
  vq_merge_k<<<64, 256, 0, stream>>>(cand_d, cand_i, idx_fin, idxf_out);
  vq_gather_loss_k<<<512, 256, 0, stream>>>(z, emb, idx_fin, q_out, loss_acc);
  vq_finalize_k<<<1, 1, 0, stream>>>(loss_acc, loss_out);
}

// Round 9
// 880.687 us; speedup vs baseline: 1.0993x; 1.0993x over previous
//
#include <hip/hip_runtime.h>

// Problem constants
#define NROWS   16384      // 16*32*32 flattened (b,h,w) rows
#define KCODES  8192
#define CDIM    256
#define HWS     1024       // 32*32
#define BSTRIDE 262144     // 256*1024 floats per batch in z / out

// Workspace layout (float-unit offsets) -- 8 slices
#define WS_AN   0                         // ||x||^2 per row       [16384]
#define WS_CE   16384                     // ||e||^2 per code      [8192]
#define WS_CD   24576                     // cand dist [n*8+slice] [131072]
#define WS_CI   155648                    // cand idx  (int)       [131072]
#define WS_IDX  286720                    // final idx (int)       [16384]
#define WS_LOSS 303104                    // loss accumulator      [1]

typedef float f32x2 __attribute__((ext_vector_type(2)));
typedef float f32x4 __attribute__((ext_vector_type(4)));

// v_pk_fma_f32: two independent fp32 FMAs per instruction. Rounds 8-9 verified
// bit-exact vs scalar chain (absmax 0).
// R10 LESSON: launch_bounds min-waves>2 spilled the asm-pair accs. Keep (256,2).
// R11 LESSON: occupancy pinned ~2 blocks/CU across all LDS/grid configs.
// R12 LESSON: prefetch-early (T14) spilled (WRITE_SIZE 8192->181K, +111us) --
// the allocator won't hold a 48-reg prefetch window across the asm compute.
// R13: step-major interleave. Old program order ran each acc's 4 DEPENDENT
// pk_fma back-to-back (chain per ri, chains sequential); in-order issue +
// unknown asm latency model => possible exposed dep latency. New order puts 8
// independent FMAs (ri 0..7) between dependent pairs. Zero register cost; the
// per-acc chain order (k3->k2->k1->k0) is unchanged -> bit-exact.
#define PKFMA_LO(acc, a, b) \
  asm("v_pk_fma_f32 %0, %1, %2, %0 op_sel:[0,0,0] op_sel_hi:[0,1,1]" \
      : "+v"(acc) : "v"(a), "v"(b))
#define PKFMA_HI(acc, a, b) \
  asm("v_pk_fma_f32 %0, %1, %2, %0 op_sel:[1,0,0] op_sel_hi:[1,1,1]" \
      : "+v"(acc) : "v"(a), "v"(b))

// -------- row norms, replicating numpy pairwise_sum order exactly --------
__global__ void rownorm_z_k(const float* __restrict__ z, float* __restrict__ An) {
#pragma clang fp contract(off)
  int n = blockIdx.x * 256 + threadIdx.x;                    // 16384 threads
  const float* base = z + ((size_t)(n >> 10)) * BSTRIDE + (n & 1023);
  float hs[2];
  for (int h = 0; h < 2; ++h) {
    float r[8];
#pragma unroll
    for (int j = 0; j < 8; ++j) { float v = base[(size_t)(h * 128 + j) * HWS]; r[j] = v * v; }
    for (int m = 1; m < 16; ++m) {
#pragma unroll
      for (int j = 0; j < 8; ++j) { float v = base[(size_t)(h * 128 + m * 8 + j) * HWS]; r[j] += v * v; }
    }
    hs[h] = ((r[0] + r[1]) + (r[2] + r[3])) + ((r[4] + r[5]) + (r[6] + r[7]));
  }
  An[n] = hs[0] + hs[1];
}

__global__ void rownorm_e_k(const float* __restrict__ emb, float* __restrict__ Ce) {
#pragma clang fp contract(off)
  int n = blockIdx.x * 256 + threadIdx.x;                    // 8192 threads
  const float* base = emb + (size_t)n * CDIM;
  float hs[2];
  for (int h = 0; h < 2; ++h) {
    float r[8];
#pragma unroll
    for (int j = 0; j < 8; ++j) { float v = base[h * 128 + j]; r[j] = v * v; }
    for (int m = 1; m < 16; ++m) {
#pragma unroll
      for (int j = 0; j < 8; ++j) { float v = base[h * 128 + m * 8 + j]; r[j] += v * v; }
    }
    hs[h] = ((r[0] + r[1]) + (r[2] + r[3])) + ((r[4] + r[5]) + (r[6] + r[7]));
  }
  Ce[n] = hs[0] + hs[1];
}

// -------- fused distance + argmin (round 13: r11 + step-major interleave) ---
// 1024 blocks = 128 row-tiles (128 rows) x 8 code-slices (1024 codes each).
// slice = bid&7 -> natural XCD affinity (dispatch round-robins bid%8 over the
// 8 XCDs; each XCD's 1MB emb slice stays L2-resident).
// Structure identical to round 11 (867us, best): loads issued at loop top,
// barrier A, ds_write, barrier B, compute, fold every 8th iter.
// Compute core: same LDS layouts, same reads; only the FMA ISSUE ORDER within
// each (g, ci2) block changes (step-major), preserving each acc's chain.
// WRITE_SIZE ~8192 is the no-spill tripwire (r10/r12 spills showed 4e6/181K).
__global__ void __launch_bounds__(256, 2)
vq_argmin_k(const float* __restrict__ z, const float* __restrict__ emb,
            const float* __restrict__ An, const float* __restrict__ Ce,
            float* __restrict__ cand_d, int* __restrict__ cand_i) {
  __shared__ float smem[12288];    // 48 KB: As=[0,4096), Bs=[4096,12288)
  float* As = smem;                // [128 rows][32 c], col XOR-swizzled by (row>>3)&7
  float* Bs = smem + 4096;         // [128 pairs][32 k][2 codes], granule-swizzled by pair&7

  const int t  = threadIdx.x;
  const int tx = t & 15;           // code group (16 codes, stride 16)
  const int ty = t >> 4;           // row group (8 consecutive rows)
  const int bid   = blockIdx.x;
  const int slice = bid & 7;       // slice s -> XCD s
  const int tile  = bid >> 3;
  const int rbase = tile * 128;    // never crosses the 1024-hw batch edge
  const int k0    = slice * 1024;

  const float* zb = z + ((size_t)(rbase >> 10)) * BSTRIDE + (rbase & 1023);

  float best[8];
  int   bidx[8];
#pragma unroll
  for (int ri = 0; ri < 8; ++ri) { best[ri] = 3.4028235e38f; bidx[ri] = 0; }

  f32x2 acc2[8][8];                // [ri][ci2]: .x = code tx+32*ci2, .y = +16
#pragma unroll
  for (int ri = 0; ri < 8; ++ri)
#pragma unroll
    for (int j = 0; j < 8; ++j) acc2[ri][j] = (f32x2){0.f, 0.f};

  // staging thread mappings (A identical to rounds 1-12)
  const int a_c   = t >> 4;         // stages c_locals {a_c, a_c+16}, 8 rows each
  const int a_hw  = (t & 15) * 8;   // 8 consecutive rows
  const int a_swr = (t & 15) & 7;   // (row>>3)&7 for all 8 staged rows
  const int a_wi  = a_c & 3;
  const int a_kg1 = a_c >> 2;       // k-group of c1 (c2 = +4)
  const int acol1 = ((a_kg1 ^ a_swr) << 2) | a_wi;        // const per thread
  const int acol2 = (((a_kg1 + 4) ^ a_swr) << 2) | a_wi;
  // B staging: thread loads 16 consecutive c of one emb row, twice (codes
  // b_code and b_code+128), scattering into the pair-interleaved layout.
  const int b_code = t >> 1;        // code 0..127 (pass adds +128)
  const int b_cb   = (t & 1) * 16;  // c_local base 0 or 16
  const int b_p    = ((b_code >> 5) << 4) | (b_code & 15); // pair row 0..63
  const int b_s    = (b_code >> 4) & 1;                    // which half of pair
  const int b_p7   = b_code & 7;                           // == pair&7 (pass-invariant)
  const int b_base = b_p * 64 + ((b_cb >> 1) << 2) + b_s;  // float units; pass1 += 4096

  const int rd_a_sw = ty & 7;
  const int rd_b_sw = tx & 7;       // == pair&7 for all this thread's pair rows
  const int bB      = tx * 64;      // pair-row base (ci2*1024 folds into offset)

  for (int kc = 0; kc < 4; ++kc) {
    const int kbase = k0 + kc * 256;
#pragma unroll 1
    for (int sc = 0; sc < 8; ++sc) {
      // short prefetch: issue just before barrier; regs die at the stores
      const float* zsrc = zb + (size_t)(sc * 32 + a_c) * HWS + a_hw;
      const float4 pa0 = *(const float4*)(zsrc);
      const float4 pa1 = *(const float4*)(zsrc + 4);
      const float4 pa2 = *(const float4*)(zsrc + 16 * HWS);
      const float4 pa3 = *(const float4*)(zsrc + 16 * HWS + 4);
      const float* bsrc0 = emb + (size_t)(kbase + b_code) * CDIM + sc * 32 + b_cb;
      const float* bsrc1 = bsrc0 + (size_t)128 * CDIM;
      const float4 pb0 = *(const float4*)(bsrc0);
      const float4 pb1 = *(const float4*)(bsrc0 + 4);
      const float4 pb2 = *(const float4*)(bsrc0 + 8);
      const float4 pb3 = *(const float4*)(bsrc0 + 12);
      const float4 pb4 = *(const float4*)(bsrc1);
      const float4 pb5 = *(const float4*)(bsrc1 + 4);
      const float4 pb6 = *(const float4*)(bsrc1 + 8);
      const float4 pb7 = *(const float4*)(bsrc1 + 12);

      __syncthreads();                      // barrier A: prior compute done
      {
        // A transpose-store: 16 scalar stores, col const per thread (2-way free)
        const float va0[8] = {pa0.x, pa0.y, pa0.z, pa0.w, pa1.x, pa1.y, pa1.z, pa1.w};
        const float va1[8] = {pa2.x, pa2.y, pa2.z, pa2.w, pa3.x, pa3.y, pa3.z, pa3.w};
#pragma unroll
        for (int j = 0; j < 8; ++j) {
          const int rb = (a_hw + j) << 5;
          As[rb + acol1] = va0[j];
          As[rb + acol2] = va1[j];
        }
        // B pair-scatter, two passes (codes +0 / +128): stride-2 pairs merge
        // into ds_write2_b32. ~4-way conflicts; stores are 1/6 of LDS ops.
        const float bval0[16] = {pb0.x, pb0.y, pb0.z, pb0.w,
                                 pb1.x, pb1.y, pb1.z, pb1.w,
                                 pb2.x, pb2.y, pb2.z, pb2.w,
                                 pb3.x, pb3.y, pb3.z, pb3.w};
        const float bval1[16] = {pb4.x, pb4.y, pb4.z, pb4.w,
                                 pb5.x, pb5.y, pb5.z, pb5.w,
                                 pb6.x, pb6.y, pb6.z, pb6.w,
                                 pb7.x, pb7.y, pb7.z, pb7.w};
#pragma unroll
        for (int i = 0; i < 8; ++i) {
          const int off = b_base + ((i ^ b_p7) << 2);
          Bs[off]            = bval0[2 * i];
          Bs[off + 2]        = bval0[2 * i + 1];
          Bs[off + 4096]     = bval1[2 * i];
          Bs[off + 4096 + 2] = bval1[2 * i + 1];
        }
      }
      __syncthreads();                      // barrier B: staged data visible

      // 8x16 micro-tile over 32 k: 2048 pk_fma, 64 A + 128 B b128 reads.
      // A fragments hoisted (av -> a01/a23 subreg views); B quads transient.
      // Step-major issue: 8 independent FMAs between dependent pairs.
#pragma unroll
      for (int g = 0; g < 8; ++g) {
        f32x2 a01[8], a23[8];
#pragma unroll
        for (int ri = 0; ri < 8; ++ri) {
          const f32x4 av = *(const f32x4*)&As[((ty * 8 + ri) << 5) + ((g ^ rd_a_sw) << 2)];
          a01[ri] = __builtin_shufflevector(av, av, 0, 1);
          a23[ri] = __builtin_shufflevector(av, av, 2, 3);
        }
        const int sw0 = ((2 * g) ^ rd_b_sw) << 2;   // granule 2g   (k 4g,4g+1)
        const int sw1 = sw0 ^ 4;                    // granule 2g+1 (k 4g+2,4g+3)
#pragma unroll
        for (int ci2 = 0; ci2 < 8; ++ci2) {
          const f32x4 b0 = *(const f32x4*)&Bs[bB + ci2 * 1024 + sw0];
          const f32x4 b1 = *(const f32x4*)&Bs[bB + ci2 * 1024 + sw1];
          const f32x2 bk0 = __builtin_shufflevector(b0, b0, 0, 1);
          const f32x2 bk1 = __builtin_shufflevector(b0, b0, 2, 3);
          const f32x2 bk2 = __builtin_shufflevector(b1, b1, 0, 1);
          const f32x2 bk3 = __builtin_shufflevector(b1, b1, 2, 3);
          // step-major: all ri at k3, then k2, k1, k0. Each acc2[ri][ci2]
          // still sees exactly HI(k3) -> LO(k2) -> HI(k1) -> LO(k0) in program
          // order -> identical lane math to rounds 1-12.
#pragma unroll
          for (int ri = 0; ri < 8; ++ri) PKFMA_HI(acc2[ri][ci2], a23[ri], bk3);
#pragma unroll
          for (int ri = 0; ri < 8; ++ri) PKFMA_LO(acc2[ri][ci2], a23[ri], bk2);
#pragma unroll
          for (int ri = 0; ri < 8; ++ri) PKFMA_HI(acc2[ri][ci2], a01[ri], bk1);
#pragma unroll
          for (int ri = 0; ri < 8; ++ri) PKFMA_LO(acc2[ri][ci2], a01[ri], bk0);
        }
      }
    }

    // fold per kc: dist = (A - 2*dot) + C with np's elementwise fp32 rounding.
    // compare order = ci ascending (ci2 .x then .y) -> identical lowest-index
    // tie semantics; cross-thread/slice merges compare indices explicitly.
    {
      const int kkb = kbase + tx;
      float cearr[16];
#pragma unroll
      for (int ci = 0; ci < 16; ++ci) cearr[ci] = Ce[kkb + ci * 16];
#pragma unroll
      for (int ri = 0; ri < 8; ++ri) {
        const float Ar = An[rbase + ty * 8 + ri];   // reload (saves live regs)
#pragma unroll
        for (int ci2 = 0; ci2 < 8; ++ci2) {
          const float d0 = (Ar - 2.0f * acc2[ri][ci2].x) + cearr[2 * ci2];
          if (d0 < best[ri]) { best[ri] = d0; bidx[ri] = kkb + ci2 * 32; }
          const float d1 = (Ar - 2.0f * acc2[ri][ci2].y) + cearr[2 * ci2 + 1];
          if (d1 < best[ri]) { best[ri] = d1; bidx[ri] = kkb + ci2 * 32 + 16; }
          acc2[ri][ci2] = (f32x2){0.f, 0.f};
        }
      }
    }
  }

  // cross-thread argmin per row (tie -> lower absolute index); alias smem
  __syncthreads();                 // compute done; safe to overwrite As/Bs
  float* redd = smem;              // [128][16]
  int*   redi = (int*)(smem + 2048);
#pragma unroll
  for (int ri = 0; ri < 8; ++ri) {
    redd[(ty * 8 + ri) * 16 + tx] = best[ri];
    redi[(ty * 8 + ri) * 16 + tx] = bidx[ri];
  }
  __syncthreads();
  if (t < 128) {
    float bd = redd[t * 16];
    int   bi = redi[t * 16];
    for (int j = 1; j < 16; ++j) {
      const float d  = redd[t * 16 + j];
      const int   i2 = redi[t * 16 + j];
      if (d < bd || (d == bd && i2 < bi)) { bd = d; bi = i2; }
    }
    const int n = rbase + t;
    cand_d[n * 8 + slice] = bd;
    cand_i[n * 8 + slice] = bi;
  }
}

// -------- merge the 8 code-slices (tie -> lower index) --------
__global__ void vq_merge_k(const float* __restrict__ cand_d, const int* __restrict__ cand_i,
                           int* __restrict__ idx_final, float* __restrict__ idxf_out) {
  const int n = blockIdx.x * 256 + threadIdx.x;   // 16384
  float bd = cand_d[n * 8];
  int   bi = cand_i[n * 8];
#pragma unroll
  for (int s = 1; s < 8; ++s) {
    const float d  = cand_d[n * 8 + s];
    const int   i2 = cand_i[n * 8 + s];
    if (d < bd || (d == bd && i2 < bi)) { bd = d; bi = i2; }
  }
  idx_final[n] = bi;
  idxf_out[n] = (float)bi;
}

// -------- gather quantized, write straight-through output, accumulate loss ----
// quantized_st = z + (q - z) in fp32 (matches np rounding; != q exactly).
__launch_bounds__(256)
__global__ void vq_gather_loss_k(const float* __restrict__ z, const float* __restrict__ emb,
                                 const int* __restrict__ idx_final,
                                 float* __restrict__ qout, float* __restrict__ loss_acc) {
  __shared__ float Qs[32 * 260];
  __shared__ int   kidx[32];
  __shared__ float warp_s[4];
  const int t = threadIdx.x;
  const int rbase = blockIdx.x * 32;
  if (t < 32) kidx[t] = idx_final[rbase + t];
  __syncthreads();
  {
    const int r = t >> 3, cp = t & 7;
    const float4* er = (const float4*)(emb + (size_t)kidx[r] * CDIM);
#pragma unroll
    for (int j = 0; j < 8; ++j) {
      const int c4 = cp + j * 8;
      const float4 v = er[c4];
      *(float4*)&Qs[r * 260 + c4 * 4] = v;
    }
  }
  __syncthreads();
  const int b = rbase >> 10, hw0 = rbase & 1023;
  const float* zb = z + (size_t)b * BSTRIDE + hw0;
  float* qb = qout + (size_t)b * BSTRIDE + hw0;
  float s = 0.f;
  const int hwl = t & 31, cg = t >> 5;
  for (int i = 0; i < 32; ++i) {
    const int c = cg * 32 + i;
    const float q  = Qs[hwl * 260 + c];
    const size_t off = (size_t)c * HWS + hwl;
    const float zv = zb[off];
    const float d  = q - zv;
    qb[off] = zv + d;          // straight-through value, np rounding
    s += d * d;
  }
  for (int off = 32; off; off >>= 1) s += __shfl_down(s, off, 64);
  if ((t & 63) == 0) warp_s[t >> 6] = s;
  __syncthreads();
  if (t == 0) atomicAdd(loss_acc, warp_s[0] + warp_s[1] + warp_s[2] + warp_s[3]);
}

__global__ void vq_finalize_k(const float* __restrict__ loss_acc, float* __restrict__ out_loss) {
  const float m = loss_acc[0] * (1.0f / 4194304.0f);
  out_loss[0] = m;          // codebook_loss
  out_loss[1] = 0.25f * m;  // commitment_loss (BETA * same mean)
}

extern "C" void kernel_launch(void* const* d_in, const int* in_sizes, int n_in,
                              void* d_out, int out_size, void* d_ws, size_t ws_size,
                              hipStream_t stream) {
  (void)in_sizes; (void)n_in; (void)out_size; (void)ws_size;
  const float* z   = (const float*)d_in[0];
  const float* emb = (const float*)d_in[1];
  float* out      = (float*)d_out;
  float* q_out    = out;                 // [16,256,32,32]
  float* loss_out = out + 4194304;       // 2 scalars
  float* idxf_out = out + 4194306;       // [16,32,32] as float

  float* ws       = (float*)d_ws;
  float* An       = ws + WS_AN;
  float* Ce       = ws + WS_CE;
  float* cand_d   = ws + WS_CD;
  int*   cand_i   = (int*)(ws + WS_CI);
  int*   idx_fin  = (int*)(ws + WS_IDX);
  float* loss_acc = ws + WS_LOSS;

  hipMemsetAsync(loss_acc, 0, sizeof(float), stream);
  rownorm_z_k<<<64, 256, 0, stream>>>(z, An);
  rownorm_e_k<<<32, 256, 0, stream>>>(emb, Ce);
  vq_argmin_k<<<1024, 256, 0, stream>>>(z, emb, An, Ce, cand_d, cand_i);
  vq_merge_k<<<64, 256, 0, stream>>>(cand_d, cand_i, idx_fin, idxf_out);
  vq_gather_loss_k<<<512, 256, 0, stream>>>(z, emb, idx_fin, q_out, loss_acc);
  vq_finalize_k<<<1, 1, 0, stream>>>(loss_acc, loss_out);
}